// Round 9
// baseline (477.468 us; speedup 1.0000x reference)
//
#include <hip/hip_runtime.h>
#include <hip/hip_bf16.h>

#define T_FRAMES 64

typedef __bf16 bf16x8 __attribute__((ext_vector_type(8)));
typedef float f32x4 __attribute__((ext_vector_type(4)));

typedef __attribute__((address_space(3))) void as3_void;
typedef __attribute__((address_space(1))) void as1_void;

__device__ __forceinline__ void gload_lds16(const void* g, void* l) {
  __builtin_amdgcn_global_load_lds((as1_void*)g, (as3_void*)l, 16, 0, 0);
}

// edge counts per level (fine->coarse): nnz = 3 * n_fine
#define NNZ0 15069
#define NNZ1 3768
#define NNZ2 942
#define NNZ3 237
#define N0 5023
#define N1 1256
#define N2 314
#define N3 79
#define N4 20

// All activation buffers are vt-major: [vert][t][C]. d_out stays [t][v][3].

// ---------------------------------------------------------------------------
// de_layers[0] -> vt-major bf16
// ---------------------------------------------------------------------------
__global__ __launch_bounds__(256) void linear0_kernel(
    const float* __restrict__ latent, const float* __restrict__ W0,
    const float* __restrict__ b0, __bf16* __restrict__ out) {
  int id = blockIdx.x * 256 + threadIdx.x;
  if (id >= 64 * 2560) return;
  int j = id % 2560;
  int t = id / 2560;
  const float* lrow = latent + t * 128;
  const float* wrow = W0 + j * 128;
  float acc = b0[j];
#pragma unroll 8
  for (int k = 0; k < 128; ++k) acc = fmaf(lrow[k], wrow[k], acc);
  out[((size_t)(j >> 7) * 64 + t) * 128 + (j & 127)] = (__bf16)acc;
}

// ---------------------------------------------------------------------------
// all weights fp32 -> bf16 (Wf zero-padded 3x288 -> 16x288)
// ---------------------------------------------------------------------------
__global__ __launch_bounds__(256) void cvt_all_kernel(
    const float* __restrict__ W1, const float* __restrict__ W2,
    const float* __restrict__ W3, const float* __restrict__ W4,
    const float* __restrict__ Wf, __bf16* __restrict__ o) {
  int i = blockIdx.x * 256 + threadIdx.x;
  if (i < 147456) { o[i] = (__bf16)W1[i]; return; }
  if (i < 221184) { o[i] = (__bf16)W2[i - 147456]; return; }
  if (i < 258048) { o[i] = (__bf16)W3[i - 221184]; return; }
  if (i < 276480) { o[i] = (__bf16)W4[i - 258048]; return; }
  if (i < 281088) {
    int j = i - 276480;
    o[i] = (j / 288 < 3) ? (__bf16)Wf[j] : (__bf16)0.f;
  }
}

// ---------------------------------------------------------------------------
// CSR build: count -> scan -> packed bucket fill ({col, val_bits})
// ---------------------------------------------------------------------------
__global__ __launch_bounds__(256) void csr_count_kernel(
    const int* __restrict__ r0, const int* __restrict__ r1,
    const int* __restrict__ r2, const int* __restrict__ r3,
    int* __restrict__ c0, int* __restrict__ c1,
    int* __restrict__ c2, int* __restrict__ c3) {
  int i = blockIdx.x * 256 + threadIdx.x;
  if (i < NNZ0) atomicAdd(&c0[r0[i]], 1);
  else if (i < NNZ0 + NNZ1) atomicAdd(&c1[r1[i - NNZ0]], 1);
  else if (i < NNZ0 + NNZ1 + NNZ2) atomicAdd(&c2[r2[i - NNZ0 - NNZ1]], 1);
  else if (i < NNZ0 + NNZ1 + NNZ2 + NNZ3) atomicAdd(&c3[r3[i - NNZ0 - NNZ1 - NNZ2]], 1);
}

__global__ __launch_bounds__(256) void csr_scan_kernel(
    const int* __restrict__ c0, const int* __restrict__ c1,
    const int* __restrict__ c2, const int* __restrict__ c3,
    int* __restrict__ o0, int* __restrict__ o1,
    int* __restrict__ o2, int* __restrict__ o3,
    int* __restrict__ u0, int* __restrict__ u1,
    int* __restrict__ u2, int* __restrict__ u3) {
  const int b = blockIdx.x;
  const int* counts = b == 0 ? c0 : b == 1 ? c1 : b == 2 ? c2 : c3;
  int* off = b == 0 ? o0 : b == 1 ? o1 : b == 2 ? o2 : o3;
  int* cur = b == 0 ? u0 : b == 1 ? u1 : b == 2 ? u2 : u3;
  const int n = b == 0 ? N0 : b == 1 ? N1 : b == 2 ? N2 : N3;

  __shared__ int part[256];
  const int chunk = (n + 255) / 256;
  const int start = threadIdx.x * chunk;
  const int end = min(start + chunk, n);
  int s = 0;
  for (int i = start; i < end; ++i) s += counts[i];
  part[threadIdx.x] = s;
  __syncthreads();
  for (int d = 1; d < 256; d <<= 1) {
    int v = (threadIdx.x >= d) ? part[threadIdx.x - d] : 0;
    __syncthreads();
    part[threadIdx.x] += v;
    __syncthreads();
  }
  int run = (threadIdx.x == 0) ? 0 : part[threadIdx.x - 1];
  for (int i = start; i < end; ++i) {
    off[i] = run;
    cur[i] = run;
    run += counts[i];
  }
  if (threadIdx.x == 255) off[n] = run;
}

__global__ __launch_bounds__(256) void csr_bucket_kernel(
    const int* __restrict__ r0, const int* __restrict__ r1,
    const int* __restrict__ r2, const int* __restrict__ r3,
    const int* __restrict__ q0, const int* __restrict__ q1,
    const int* __restrict__ q2, const int* __restrict__ q3,
    const float* __restrict__ v0, const float* __restrict__ v1,
    const float* __restrict__ v2, const float* __restrict__ v3,
    int* __restrict__ u0, int* __restrict__ u1,
    int* __restrict__ u2, int* __restrict__ u3,
    int2* __restrict__ p0, int2* __restrict__ p1,
    int2* __restrict__ p2, int2* __restrict__ p3) {
  int i = blockIdx.x * 256 + threadIdx.x;
  if (i < NNZ0) {
    int p = atomicAdd(&u0[r0[i]], 1);
    p0[p] = make_int2(q0[i], __float_as_int(v0[i]));
  } else if (i < NNZ0 + NNZ1) {
    int e = i - NNZ0;
    int p = atomicAdd(&u1[r1[e]], 1);
    p1[p] = make_int2(q1[e], __float_as_int(v1[e]));
  } else if (i < NNZ0 + NNZ1 + NNZ2) {
    int e = i - NNZ0 - NNZ1;
    int p = atomicAdd(&u2[r2[e]], 1);
    p2[p] = make_int2(q2[e], __float_as_int(v2[e]));
  } else if (i < NNZ0 + NNZ1 + NNZ2 + NNZ3) {
    int e = i - NNZ0 - NNZ1 - NNZ2;
    int p = atomicAdd(&u3[r3[e]], 1);
    p3[p] = make_int2(q3[e], __float_as_int(v3[e]));
  }
}

// ---------------------------------------------------------------------------
// CSR gather pool, vt-major (not a top dispatch; unchanged)
// ---------------------------------------------------------------------------
template <int C, int TT>
__global__ __launch_bounds__(256) void pool_csr_kernel(
    const __bf16* __restrict__ x, const int* __restrict__ off,
    const int2* __restrict__ pk, __bf16* __restrict__ out, int n_out) {
  unsigned id = blockIdx.x * 256u + threadIdx.x;
  unsigned total = (unsigned)n_out * (T_FRAMES / TT) * C;
  if (id >= total) return;
  const int c = id % C;
  const unsigned rt = id / C;
  const int tb = rt % (T_FRAMES / TT);
  const int row = rt / (T_FRAMES / TT);

  const int o0 = off[row], o1 = off[row + 1];
  float acc[TT];
#pragma unroll
  for (int u = 0; u < TT; ++u) acc[u] = 0.f;

  for (int j = o0; j < o1; ++j) {
    const int2 rec = pk[j];
    const float val = __int_as_float(rec.y);
    const __bf16* xp = x + ((size_t)rec.x * T_FRAMES + tb * TT) * C + c;
#pragma unroll
    for (int u = 0; u < TT; ++u)
      acc[u] = fmaf(val, (float)xp[(size_t)u * C], acc[u]);
  }

  __bf16* op = out + ((size_t)row * T_FRAMES + tb * TT) * C + c;
#pragma unroll
  for (int u = 0; u < TT; ++u) op[(size_t)u * C] = (__bf16)acc[u];
}

// ---------------------------------------------------------------------------
// conv via async LDS-DMA staging (CIN=64 levels + structure for CIN=32):
// block = one vertex, 4 waves (wave w = t-tile w). Each wave issues its KK
// A-fragment loads as global_load_lds (per-lane source, linear LDS dest in
// exact fragment order [wave][kk][lane]*16B), then vmcnt(0)+sched_barrier,
// then conflict-free lane-contiguous ds_read_b128 + MFMA. No __syncthreads:
// each wave reads only its own staging. Loads stay in flight without VGPRs
// (R7/R8 evidence: compiler refuses to hold a VGPR-resident prefetch).
// ---------------------------------------------------------------------------
template <int CIN, int COUT>
__global__ __launch_bounds__(256) void conv_lds_kernel(
    const __bf16* __restrict__ x, const int* __restrict__ idx,
    const __bf16* __restrict__ Wb, const float* __restrict__ bias,
    __bf16* __restrict__ out) {
  constexpr int K = 9 * CIN;
  constexpr int KK = K / 32;           // fragments per t-row
  constexpr int NT = COUT / 16;
  constexpr int SC = CIN / 32;         // kk-fragments per spiral slab

  __shared__ __bf16 frag[4 * KK * 512];   // [wave][kk][lane]*8 elems

  const int lane = threadIdx.x & 63;
  const int wid = threadIdx.x >> 6;    // t-tile 0..3
  const int v = blockIdx.x;
  const int col = lane & 15;
  const int kg = lane >> 4;

  // ---- stage: wave-private async LDS-DMA, 9*SC independent 1KB loads ----
#pragma unroll
  for (int s = 0; s < 9; ++s) {
    const __bf16* sp = x + (size_t)idx[v * 9 + s] * (T_FRAMES * CIN)
                         + (size_t)(wid * 16 + col) * CIN + kg * 8;
#pragma unroll
    for (int c = 0; c < SC; ++c) {
      const int kk = s * SC + c;
      gload_lds16(sp + c * 32, &frag[(wid * KK + kk) * 512]);
    }
  }
  asm volatile("s_waitcnt vmcnt(0)" ::: "memory");
  __builtin_amdgcn_sched_barrier(0);

  f32x4 acc[NT];
#pragma unroll
  for (int nt = 0; nt < NT; ++nt) {
    float b = bias[nt * 16 + col];
    acc[nt] = (f32x4){b, b, b, b};
  }

  // ---- compute: lane-contiguous LDS fragments + L2-resident W ----
#pragma unroll
  for (int kk = 0; kk < KK; ++kk) {
    bf16x8 a = *(const bf16x8*)&frag[(wid * KK + kk) * 512 + lane * 8];
#pragma unroll
    for (int nt = 0; nt < NT; ++nt) {
      bf16x8 bfr = *(const bf16x8*)(Wb + (size_t)(nt * 16 + col) * K + kk * 32 + kg * 8);
      acc[nt] = __builtin_amdgcn_mfma_f32_16x16x32_bf16(a, bfr, acc[nt], 0, 0, 0);
    }
  }

  // ---- store (D: col=channel, row kg*4+j = t within tile), ELU, vt-major ----
#pragma unroll
  for (int j = 0; j < 4; ++j) {
    const size_t tr = (size_t)wid * 16 + kg * 4 + j;
#pragma unroll
    for (int nt = 0; nt < NT; ++nt) {
      float aa = acc[nt][j];
      aa = aa > 0.f ? aa : expm1f(aa);   // ELU
      out[((size_t)v * T_FRAMES + tr) * COUT + nt * 16 + col] = (__bf16)aa;
    }
  }
}

// ---------------------------------------------------------------------------
// spiral conv MFMA for the tiny CIN=128 levels (R7 form, MT m-tiles/wave)
// ---------------------------------------------------------------------------
template <int CIN, int COUT, int WV, int MT>
__global__ __launch_bounds__(WV * 64) void conv_mfma_kernel(
    const __bf16* __restrict__ x, const int* __restrict__ idx,
    const __bf16* __restrict__ Wb, const float* __restrict__ bias,
    __bf16* __restrict__ out) {
  constexpr int K = 9 * CIN;
  constexpr int KK = K / 32;
  constexpr int NT = COUT / 16;

  const int lane = threadIdx.x & 63;
  const int wid = threadIdx.x >> 6;
  const int v = blockIdx.x;
  const int tq0 = (blockIdx.y * WV + wid) * MT;
  const int col = lane & 15;
  const int kg = lane >> 4;

  size_t vbase[9];
#pragma unroll
  for (int s = 0; s < 9; ++s)
    vbase[s] = (size_t)idx[v * 9 + s] * (T_FRAMES * CIN);

  bf16x8 a[MT][KK];
#pragma unroll
  for (int mt = 0; mt < MT; ++mt) {
    const size_t trow = (size_t)(tq0 + mt) * 16 + col;
#pragma unroll
    for (int kk = 0; kk < KK; ++kk) {
      const int s = (kk * 32) / CIN;
      const int ci0 = (kk * 32) % CIN;
      a[mt][kk] = *(const bf16x8*)(x + vbase[s] + trow * CIN + ci0 + kg * 8);
    }
  }

  f32x4 acc[MT][NT];
#pragma unroll
  for (int nt = 0; nt < NT; ++nt) {
    float b = bias[nt * 16 + col];
#pragma unroll
    for (int mt = 0; mt < MT; ++mt) acc[mt][nt] = (f32x4){b, b, b, b};
  }

#pragma unroll
  for (int kk = 0; kk < KK; ++kk) {
#pragma unroll
    for (int nt = 0; nt < NT; ++nt) {
      bf16x8 bfr = *(const bf16x8*)(Wb + (size_t)(nt * 16 + col) * K + kk * 32 + kg * 8);
#pragma unroll
      for (int mt = 0; mt < MT; ++mt)
        acc[mt][nt] = __builtin_amdgcn_mfma_f32_16x16x32_bf16(a[mt][kk], bfr, acc[mt][nt], 0, 0, 0);
    }
  }

#pragma unroll
  for (int mt = 0; mt < MT; ++mt) {
#pragma unroll
    for (int j = 0; j < 4; ++j) {
      const size_t tr = (size_t)(tq0 + mt) * 16 + kg * 4 + j;
#pragma unroll
      for (int nt = 0; nt < NT; ++nt) {
        float aa = acc[mt][nt][j];
        aa = aa > 0.f ? aa : expm1f(aa);
        out[((size_t)v * T_FRAMES + tr) * COUT + nt * 16 + col] = (__bf16)aa;
      }
    }
  }
}

// ---------------------------------------------------------------------------
// final conv 32->3 (+actor) with async LDS-DMA staging, [t][v][3] output.
// ---------------------------------------------------------------------------
__global__ __launch_bounds__(256) void final_lds_kernel(
    const __bf16* __restrict__ x, const int* __restrict__ idx,
    const __bf16* __restrict__ Wfp, const float* __restrict__ bf3,
    const float* __restrict__ actor, float* __restrict__ out) {
  __shared__ __bf16 frag[4 * 9 * 512];   // 36 KB

  const int lane = threadIdx.x & 63;
  const int wid = threadIdx.x >> 6;
  const int v = blockIdx.x;
  const int col = lane & 15;
  const int kg = lane >> 4;

#pragma unroll
  for (int s = 0; s < 9; ++s) {
    const __bf16* sp = x + (size_t)idx[v * 9 + s] * (T_FRAMES * 32)
                         + (size_t)(wid * 16 + col) * 32 + kg * 8;
    gload_lds16(sp, &frag[(wid * 9 + s) * 512]);
  }
  asm volatile("s_waitcnt vmcnt(0)" ::: "memory");
  __builtin_amdgcn_sched_barrier(0);

  float b = (col < 3) ? bf3[col] : 0.f;
  f32x4 acc = (f32x4){b, b, b, b};

#pragma unroll
  for (int kk = 0; kk < 9; ++kk) {
    bf16x8 a = *(const bf16x8*)&frag[(wid * 9 + kk) * 512 + lane * 8];
    bf16x8 w = *(const bf16x8*)(Wfp + col * 288 + kk * 32 + kg * 8);
    acc = __builtin_amdgcn_mfma_f32_16x16x32_bf16(a, w, acc, 0, 0, 0);
  }

  if (col < 3) {
    const float av = actor[v * 3 + col];
#pragma unroll
    for (int j = 0; j < 4; ++j) {
      const int tr = wid * 16 + kg * 4 + j;
      out[((size_t)tr * N0 + v) * 3 + col] = acc[j] + av;
    }
  }
}

// ---------------------------------------------------------------------------
extern "C" void kernel_launch(void* const* d_in, const int* in_sizes, int n_in_args,
                              void* d_out, int out_size, void* d_ws, size_t ws_size,
                              hipStream_t stream) {
  const float* latent = (const float*)d_in[0];
  const float* actor  = (const float*)d_in[1];
  const int* spiral0 = (const int*)d_in[2];
  const int* spiral1 = (const int*)d_in[3];
  const int* spiral2 = (const int*)d_in[4];
  const int* spiral3 = (const int*)d_in[5];
  const int* up0_rows = (const int*)d_in[6];
  const int* up0_cols = (const int*)d_in[7];
  const float* up0_vals = (const float*)d_in[8];
  const int* up1_rows = (const int*)d_in[9];
  const int* up1_cols = (const int*)d_in[10];
  const float* up1_vals = (const float*)d_in[11];
  const int* up2_rows = (const int*)d_in[12];
  const int* up2_cols = (const int*)d_in[13];
  const float* up2_vals = (const float*)d_in[14];
  const int* up3_rows = (const int*)d_in[15];
  const int* up3_cols = (const int*)d_in[16];
  const float* up3_vals = (const float*)d_in[17];
  const float* W0 = (const float*)d_in[18];
  const float* b0 = (const float*)d_in[19];
  const float* W1 = (const float*)d_in[20];
  const float* b1 = (const float*)d_in[21];
  const float* W2 = (const float*)d_in[22];
  const float* b2 = (const float*)d_in[23];
  const float* W3 = (const float*)d_in[24];
  const float* b3 = (const float*)d_in[25];
  const float* W4 = (const float*)d_in[26];
  const float* b4 = (const float*)d_in[27];
  const float* Wf = (const float*)d_in[28];
  const float* bf3 = (const float*)d_in[29];
  float* out = (float*)d_out;

  // ---- workspace layout (~62.5 MB) ----
  __bf16* poolbuf = (__bf16*)d_ws;              // 20,574,208 bf16 (41.1 MB)
  __bf16* convout = poolbuf + 20574208;         // 10,287,104 bf16 (20.6 MB)
  __bf16* wbuf = convout + 10287104;            // 281,088 bf16 (0.56 MB)
  __bf16* W1b = wbuf;                           // 128*1152
  __bf16* W2b = W1b + 147456;                   // 64*1152
  __bf16* W3b = W2b + 73728;                    // 64*576
  __bf16* W4b = W3b + 36864;                    // 32*576
  __bf16* Wfp = W4b + 18432;                    // 16*288 zero-padded
  int* csr = (int*)(wbuf + 281088);
  int* cnt0 = csr;            int* cnt1 = cnt0 + N0;   int* cnt2 = cnt1 + N1;   int* cnt3 = cnt2 + N2;
  int* off0 = csr + 6672;     int* off1 = off0 + N0+1; int* off2 = off1 + N1+1; int* off3 = off2 + N2+1;
  int* cur0 = csr + 13348;    int* cur1 = cur0 + N0;   int* cur2 = cur1 + N1;   int* cur3 = cur2 + N2;
  int2* pk0 = (int2*)(csr + 20020);             // 8B aligned
  int2* pk1 = pk0 + NNZ0;
  int2* pk2 = pk1 + NNZ1;
  int2* pk3 = pk2 + NNZ2;

  // ---- CSR build ----
  hipMemsetAsync(cnt0, 0, 6672 * sizeof(int), stream);
  csr_count_kernel<<<(20016 + 255) / 256, 256, 0, stream>>>(
      up0_rows, up1_rows, up2_rows, up3_rows, cnt0, cnt1, cnt2, cnt3);
  csr_scan_kernel<<<4, 256, 0, stream>>>(cnt0, cnt1, cnt2, cnt3,
                                         off0, off1, off2, off3,
                                         cur0, cur1, cur2, cur3);
  csr_bucket_kernel<<<(20016 + 255) / 256, 256, 0, stream>>>(
      up0_rows, up1_rows, up2_rows, up3_rows,
      up0_cols, up1_cols, up2_cols, up3_cols,
      up0_vals, up1_vals, up2_vals, up3_vals,
      cur0, cur1, cur2, cur3, pk0, pk1, pk2, pk3);

  // ---- weights -> bf16 ----
  cvt_all_kernel<<<(281088 + 255) / 256, 256, 0, stream>>>(W1, W2, W3, W4, Wf, wbuf);

  // ---- dense: latent -> [20][64][128] bf16 (vt-major) ----
  linear0_kernel<<<(64 * 2560 + 255) / 256, 256, 0, stream>>>(latent, W0, b0, convout);

  // ---- level 3: pool 20->79 (C=128), conv 128->128 (R7 form) ----
  pool_csr_kernel<128, 16><<<(N3 * 4 * 128 + 255) / 256, 256, 0, stream>>>(
      convout, off3, pk3, poolbuf, N3);
  conv_mfma_kernel<128, 128, 1, 1><<<dim3(N3, 4), 64, 0, stream>>>(
      poolbuf, spiral3, W1b, b1, convout);

  // ---- level 2: pool 79->314 (C=128), conv 128->64 (R7 form) ----
  pool_csr_kernel<128, 16><<<(N2 * 4 * 128 + 255) / 256, 256, 0, stream>>>(
      convout, off2, pk2, poolbuf, N2);
  conv_mfma_kernel<128, 64, 1, 1><<<dim3(N2, 4), 64, 0, stream>>>(
      poolbuf, spiral2, W2b, b2, convout);

  // ---- level 1: pool 314->1256 (C=64), conv 64->64 (async LDS-DMA) ----
  pool_csr_kernel<64, 16><<<(N1 * 4 * 64 + 255) / 256, 256, 0, stream>>>(
      convout, off1, pk1, poolbuf, N1);
  conv_lds_kernel<64, 64><<<N1, 256, 0, stream>>>(poolbuf, spiral1, W3b, b3, convout);

  // ---- level 0: pool 1256->5023 (C=64), conv 64->32 (async LDS-DMA) ----
  pool_csr_kernel<64, 16><<<(N0 * 4 * 64 + 255) / 256, 256, 0, stream>>>(
      convout, off0, pk0, poolbuf, N0);
  conv_lds_kernel<64, 32><<<N0, 256, 0, stream>>>(poolbuf, spiral0, W4b, b4, convout);

  // ---- final conv 32->3 + actor (async LDS-DMA, [t][v][3] output) ----
  final_lds_kernel<<<N0, 256, 0, stream>>>(convout, spiral0, Wfp, bf3, actor, out);
}

// Round 11
// 407.264 us; speedup vs baseline: 1.1724x; 1.1724x over previous
//
#include <hip/hip_runtime.h>
#include <hip/hip_bf16.h>

#define T_FRAMES 64

typedef __bf16 bf16x8 __attribute__((ext_vector_type(8)));
typedef __bf16 bf16x4 __attribute__((ext_vector_type(4)));
typedef float f32x4 __attribute__((ext_vector_type(4)));

// edge counts per level (fine->coarse): nnz = 3 * n_fine
#define NNZ0 15069
#define NNZ1 3768
#define NNZ2 942
#define NNZ3 237
#define N0 5023
#define N1 1256
#define N2 314
#define N3 79
#define N4 20

// All activation buffers are vt-major: [vert][t][C]. d_out stays [t][v][3].

// ---------------------------------------------------------------------------
// de_layers[0] -> vt-major bf16
// ---------------------------------------------------------------------------
__global__ __launch_bounds__(256) void linear0_kernel(
    const float* __restrict__ latent, const float* __restrict__ W0,
    const float* __restrict__ b0, __bf16* __restrict__ out) {
  int id = blockIdx.x * 256 + threadIdx.x;
  if (id >= 64 * 2560) return;
  int j = id % 2560;
  int t = id / 2560;
  const float* lrow = latent + t * 128;
  const float* wrow = W0 + j * 128;
  float acc = b0[j];
#pragma unroll 8
  for (int k = 0; k < 128; ++k) acc = fmaf(lrow[k], wrow[k], acc);
  out[((size_t)(j >> 7) * 64 + t) * 128 + (j & 127)] = (__bf16)acc;
}

// ---------------------------------------------------------------------------
// all weights fp32 -> bf16 (Wf zero-padded 3x288 -> 16x288)
// ---------------------------------------------------------------------------
__global__ __launch_bounds__(256) void cvt_all_kernel(
    const float* __restrict__ W1, const float* __restrict__ W2,
    const float* __restrict__ W3, const float* __restrict__ W4,
    const float* __restrict__ Wf, __bf16* __restrict__ o) {
  int i = blockIdx.x * 256 + threadIdx.x;
  if (i < 147456) { o[i] = (__bf16)W1[i]; return; }
  if (i < 221184) { o[i] = (__bf16)W2[i - 147456]; return; }
  if (i < 258048) { o[i] = (__bf16)W3[i - 221184]; return; }
  if (i < 276480) { o[i] = (__bf16)W4[i - 258048]; return; }
  if (i < 281088) {
    int j = i - 276480;
    o[i] = (j / 288 < 3) ? (__bf16)Wf[j] : (__bf16)0.f;
  }
}

// ---------------------------------------------------------------------------
// CSR build: count -> scan -> packed bucket fill ({col, val_bits})
// ---------------------------------------------------------------------------
__global__ __launch_bounds__(256) void csr_count_kernel(
    const int* __restrict__ r0, const int* __restrict__ r1,
    const int* __restrict__ r2, const int* __restrict__ r3,
    int* __restrict__ c0, int* __restrict__ c1,
    int* __restrict__ c2, int* __restrict__ c3) {
  int i = blockIdx.x * 256 + threadIdx.x;
  if (i < NNZ0) atomicAdd(&c0[r0[i]], 1);
  else if (i < NNZ0 + NNZ1) atomicAdd(&c1[r1[i - NNZ0]], 1);
  else if (i < NNZ0 + NNZ1 + NNZ2) atomicAdd(&c2[r2[i - NNZ0 - NNZ1]], 1);
  else if (i < NNZ0 + NNZ1 + NNZ2 + NNZ3) atomicAdd(&c3[r3[i - NNZ0 - NNZ1 - NNZ2]], 1);
}

__global__ __launch_bounds__(256) void csr_scan_kernel(
    const int* __restrict__ c0, const int* __restrict__ c1,
    const int* __restrict__ c2, const int* __restrict__ c3,
    int* __restrict__ o0, int* __restrict__ o1,
    int* __restrict__ o2, int* __restrict__ o3,
    int* __restrict__ u0, int* __restrict__ u1,
    int* __restrict__ u2, int* __restrict__ u3) {
  const int b = blockIdx.x;
  const int* counts = b == 0 ? c0 : b == 1 ? c1 : b == 2 ? c2 : c3;
  int* off = b == 0 ? o0 : b == 1 ? o1 : b == 2 ? o2 : o3;
  int* cur = b == 0 ? u0 : b == 1 ? u1 : b == 2 ? u2 : u3;
  const int n = b == 0 ? N0 : b == 1 ? N1 : b == 2 ? N2 : N3;

  __shared__ int part[256];
  const int chunk = (n + 255) / 256;
  const int start = threadIdx.x * chunk;
  const int end = min(start + chunk, n);
  int s = 0;
  for (int i = start; i < end; ++i) s += counts[i];
  part[threadIdx.x] = s;
  __syncthreads();
  for (int d = 1; d < 256; d <<= 1) {
    int v = (threadIdx.x >= d) ? part[threadIdx.x - d] : 0;
    __syncthreads();
    part[threadIdx.x] += v;
    __syncthreads();
  }
  int run = (threadIdx.x == 0) ? 0 : part[threadIdx.x - 1];
  for (int i = start; i < end; ++i) {
    off[i] = run;
    cur[i] = run;
    run += counts[i];
  }
  if (threadIdx.x == 255) off[n] = run;
}

__global__ __launch_bounds__(256) void csr_bucket_kernel(
    const int* __restrict__ r0, const int* __restrict__ r1,
    const int* __restrict__ r2, const int* __restrict__ r3,
    const int* __restrict__ q0, const int* __restrict__ q1,
    const int* __restrict__ q2, const int* __restrict__ q3,
    const float* __restrict__ v0, const float* __restrict__ v1,
    const float* __restrict__ v2, const float* __restrict__ v3,
    int* __restrict__ u0, int* __restrict__ u1,
    int* __restrict__ u2, int* __restrict__ u3,
    int2* __restrict__ p0, int2* __restrict__ p1,
    int2* __restrict__ p2, int2* __restrict__ p3) {
  int i = blockIdx.x * 256 + threadIdx.x;
  if (i < NNZ0) {
    int p = atomicAdd(&u0[r0[i]], 1);
    p0[p] = make_int2(q0[i], __float_as_int(v0[i]));
  } else if (i < NNZ0 + NNZ1) {
    int e = i - NNZ0;
    int p = atomicAdd(&u1[r1[e]], 1);
    p1[p] = make_int2(q1[e], __float_as_int(v1[e]));
  } else if (i < NNZ0 + NNZ1 + NNZ2) {
    int e = i - NNZ0 - NNZ1;
    int p = atomicAdd(&u2[r2[e]], 1);
    p2[p] = make_int2(q2[e], __float_as_int(v2[e]));
  } else if (i < NNZ0 + NNZ1 + NNZ2 + NNZ3) {
    int e = i - NNZ0 - NNZ1 - NNZ2;
    int p = atomicAdd(&u3[r3[e]], 1);
    p3[p] = make_int2(q3[e], __float_as_int(v3[e]));
  }
}

// ---------------------------------------------------------------------------
// CSR gather pool, vt-major
// ---------------------------------------------------------------------------
template <int C, int TT>
__global__ __launch_bounds__(256) void pool_csr_kernel(
    const __bf16* __restrict__ x, const int* __restrict__ off,
    const int2* __restrict__ pk, __bf16* __restrict__ out, int n_out) {
  unsigned id = blockIdx.x * 256u + threadIdx.x;
  unsigned total = (unsigned)n_out * (T_FRAMES / TT) * C;
  if (id >= total) return;
  const int c = id % C;
  const unsigned rt = id / C;
  const int tb = rt % (T_FRAMES / TT);
  const int row = rt / (T_FRAMES / TT);

  const int o0 = off[row], o1 = off[row + 1];
  float acc[TT];
#pragma unroll
  for (int u = 0; u < TT; ++u) acc[u] = 0.f;

  for (int j = o0; j < o1; ++j) {
    const int2 rec = pk[j];
    const float val = __int_as_float(rec.y);
    const __bf16* xp = x + ((size_t)rec.x * T_FRAMES + tb * TT) * C + c;
#pragma unroll
    for (int u = 0; u < TT; ++u)
      acc[u] = fmaf(val, (float)xp[(size_t)u * C], acc[u]);
  }

  __bf16* op = out + ((size_t)row * T_FRAMES + tb * TT) * C + c;
#pragma unroll
  for (int u = 0; u < TT; ++u) op[(size_t)u * C] = (__bf16)acc[u];
}

// ---------------------------------------------------------------------------
// spiral conv MFMA, vt-major (R7 form: MT m-tiles/wave, no fences).
// R6-R9 established: random-slab gather is fabric-BW-bound at ~1.9 TB/s;
// WV=2,MT=2 is the measured-best concurrency point (89us for conv0).
// ---------------------------------------------------------------------------
template <int CIN, int COUT, int WV, int MT>
__global__ __launch_bounds__(WV * 64) void conv_mfma_kernel(
    const __bf16* __restrict__ x, const int* __restrict__ idx,
    const __bf16* __restrict__ Wb, const float* __restrict__ bias,
    __bf16* __restrict__ out) {
  constexpr int K = 9 * CIN;
  constexpr int KK = K / 32;
  constexpr int NT = COUT / 16;

  const int lane = threadIdx.x & 63;
  const int wid = threadIdx.x >> 6;
  const int v = blockIdx.x;
  const int tq0 = (blockIdx.y * WV + wid) * MT;
  const int col = lane & 15;
  const int kg = lane >> 4;

  size_t vbase[9];
#pragma unroll
  for (int s = 0; s < 9; ++s)
    vbase[s] = (size_t)idx[v * 9 + s] * (T_FRAMES * CIN);

  bf16x8 a[MT][KK];
#pragma unroll
  for (int mt = 0; mt < MT; ++mt) {
    const size_t trow = (size_t)(tq0 + mt) * 16 + col;
#pragma unroll
    for (int kk = 0; kk < KK; ++kk) {
      const int s = (kk * 32) / CIN;
      const int ci0 = (kk * 32) % CIN;
      a[mt][kk] = *(const bf16x8*)(x + vbase[s] + trow * CIN + ci0 + kg * 8);
    }
  }

  f32x4 acc[MT][NT];
#pragma unroll
  for (int nt = 0; nt < NT; ++nt) {
    float b = bias[nt * 16 + col];
#pragma unroll
    for (int mt = 0; mt < MT; ++mt) acc[mt][nt] = (f32x4){b, b, b, b};
  }

#pragma unroll
  for (int kk = 0; kk < KK; ++kk) {
#pragma unroll
    for (int nt = 0; nt < NT; ++nt) {
      bf16x8 bfr = *(const bf16x8*)(Wb + (size_t)(nt * 16 + col) * K + kk * 32 + kg * 8);
#pragma unroll
      for (int mt = 0; mt < MT; ++mt)
        acc[mt][nt] = __builtin_amdgcn_mfma_f32_16x16x32_bf16(a[mt][kk], bfr, acc[mt][nt], 0, 0, 0);
    }
  }

#pragma unroll
  for (int mt = 0; mt < MT; ++mt) {
#pragma unroll
    for (int j = 0; j < 4; ++j) {
      const size_t tr = (size_t)(tq0 + mt) * 16 + kg * 4 + j;
#pragma unroll
      for (int nt = 0; nt < NT; ++nt) {
        float aa = acc[mt][nt][j];
        aa = aa > 0.f ? aa : expm1f(aa);
        out[((size_t)v * T_FRAMES + tr) * COUT + nt * 16 + col] = (__bf16)aa;
      }
    }
  }
}

// ---------------------------------------------------------------------------
// FINAL CONV, restructured (dense transform + once-each gather-sum):
// Stage A (dense): Z[u][s][t][c] = sum_ci z[u][t][ci] * Wf[c, s*32+ci]
//   block = input vertex u, 4 waves (t-tiles); reads z[u] densely, 9 MFMAs
//   per wave (one per s, K=32), writes 512B Z-slab per (u,s). No gather.
// ---------------------------------------------------------------------------
__global__ __launch_bounds__(256) void final_dense_kernel(
    const __bf16* __restrict__ z, const __bf16* __restrict__ Wfp,
    __bf16* __restrict__ Z) {
  const int lane = threadIdx.x & 63;
  const int wid = threadIdx.x >> 6;
  const int u = blockIdx.x;
  const int col = lane & 15;
  const int kg = lane >> 4;
  const size_t trow = (size_t)wid * 16 + col;

  // A-fragment: 8 contiguous channels (kg*8..) of z[u][trow][:], K=32
  const bf16x8 a = *(const bf16x8*)(z + ((size_t)u * T_FRAMES + trow) * 32 + kg * 8);

#pragma unroll
  for (int s = 0; s < 9; ++s) {
    const bf16x8 w = *(const bf16x8*)(Wfp + col * 288 + s * 32 + kg * 8);
    f32x4 acc = (f32x4){0.f, 0.f, 0.f, 0.f};
    acc = __builtin_amdgcn_mfma_f32_16x16x32_bf16(a, w, acc, 0, 0, 0);
    if (col < 4) {
      // D: row = kg*4+j (t within tile), col = output channel
#pragma unroll
      for (int j = 0; j < 4; ++j) {
        const size_t tr = (size_t)wid * 16 + kg * 4 + j;
        Z[(((size_t)u * 9 + s) * T_FRAMES + tr) * 4 + col] = (__bf16)acc[j];
      }
    }
  }
}

// ---------------------------------------------------------------------------
// Stage B: out[t][v][c] = sum_s Z[idx[v,s]][s][t][c] + bf[c] + actor[v][c]
// wave = one v (idx loads scalar), lane = t -> 512B contiguous read per
// (v,s); each Z slab read ~once (no re-read amplification).
// ---------------------------------------------------------------------------
__global__ __launch_bounds__(256) void final_gather_kernel(
    const __bf16* __restrict__ Z, const int* __restrict__ idx,
    const float* __restrict__ bf3, const float* __restrict__ actor,
    float* __restrict__ out) {
  const unsigned id = blockIdx.x * 256u + threadIdx.x;
  if (id >= (unsigned)N0 * T_FRAMES) return;
  const int t = id & 63;
  const int v = id >> 6;

  float a0 = bf3[0], a1 = bf3[1], a2 = bf3[2];
#pragma unroll
  for (int s = 0; s < 9; ++s) {
    const int u = idx[v * 9 + s];
    const bf16x4 zz = *(const bf16x4*)(Z + (((size_t)u * 9 + s) * T_FRAMES + t) * 4);
    a0 += (float)zz[0];
    a1 += (float)zz[1];
    a2 += (float)zz[2];
  }
  float* op = out + ((size_t)t * N0 + v) * 3;
  op[0] = a0 + actor[v * 3 + 0];
  op[1] = a1 + actor[v * 3 + 1];
  op[2] = a2 + actor[v * 3 + 2];
}

// ---------------------------------------------------------------------------
extern "C" void kernel_launch(void* const* d_in, const int* in_sizes, int n_in_args,
                              void* d_out, int out_size, void* d_ws, size_t ws_size,
                              hipStream_t stream) {
  const float* latent = (const float*)d_in[0];
  const float* actor  = (const float*)d_in[1];
  const int* spiral0 = (const int*)d_in[2];
  const int* spiral1 = (const int*)d_in[3];
  const int* spiral2 = (const int*)d_in[4];
  const int* spiral3 = (const int*)d_in[5];
  const int* up0_rows = (const int*)d_in[6];
  const int* up0_cols = (const int*)d_in[7];
  const float* up0_vals = (const float*)d_in[8];
  const int* up1_rows = (const int*)d_in[9];
  const int* up1_cols = (const int*)d_in[10];
  const float* up1_vals = (const float*)d_in[11];
  const int* up2_rows = (const int*)d_in[12];
  const int* up2_cols = (const int*)d_in[13];
  const float* up2_vals = (const float*)d_in[14];
  const int* up3_rows = (const int*)d_in[15];
  const int* up3_cols = (const int*)d_in[16];
  const float* up3_vals = (const float*)d_in[17];
  const float* W0 = (const float*)d_in[18];
  const float* b0 = (const float*)d_in[19];
  const float* W1 = (const float*)d_in[20];
  const float* b1 = (const float*)d_in[21];
  const float* W2 = (const float*)d_in[22];
  const float* b2 = (const float*)d_in[23];
  const float* W3 = (const float*)d_in[24];
  const float* b3 = (const float*)d_in[25];
  const float* W4 = (const float*)d_in[26];
  const float* b4 = (const float*)d_in[27];
  const float* Wf = (const float*)d_in[28];
  const float* bf3 = (const float*)d_in[29];
  float* out = (float*)d_out;

  // ---- workspace layout (~62.5 MB) ----
  __bf16* poolbuf = (__bf16*)d_ws;              // 20,574,208 bf16 (41.1 MB)
  __bf16* convout = poolbuf + 20574208;         // 10,287,104 bf16 (20.6 MB)
  __bf16* wbuf = convout + 10287104;            // 281,088 bf16 (0.56 MB)
  __bf16* W1b = wbuf;                           // 128*1152
  __bf16* W2b = W1b + 147456;                   // 64*1152
  __bf16* W3b = W2b + 73728;                    // 64*576
  __bf16* W4b = W3b + 36864;                    // 32*576
  __bf16* Wfp = W4b + 18432;                    // 16*288 zero-padded
  int* csr = (int*)(wbuf + 281088);
  int* cnt0 = csr;            int* cnt1 = cnt0 + N0;   int* cnt2 = cnt1 + N1;   int* cnt3 = cnt2 + N2;
  int* off0 = csr + 6672;     int* off1 = off0 + N0+1; int* off2 = off1 + N1+1; int* off3 = off2 + N2+1;
  int* cur0 = csr + 13348;    int* cur1 = cur0 + N0;   int* cur2 = cur1 + N1;   int* cur3 = cur2 + N2;
  int2* pk0 = (int2*)(csr + 20020);             // 8B aligned
  int2* pk1 = pk0 + NNZ0;
  int2* pk2 = pk1 + NNZ1;
  int2* pk3 = pk2 + NNZ2;
  // Z reuses poolbuf (dead after conv0 consumed it): 5023*9*64*4 bf16 = 23.1MB
  __bf16* Zbuf = poolbuf;

  // ---- CSR build ----
  hipMemsetAsync(cnt0, 0, 6672 * sizeof(int), stream);
  csr_count_kernel<<<(20016 + 255) / 256, 256, 0, stream>>>(
      up0_rows, up1_rows, up2_rows, up3_rows, cnt0, cnt1, cnt2, cnt3);
  csr_scan_kernel<<<4, 256, 0, stream>>>(cnt0, cnt1, cnt2, cnt3,
                                         off0, off1, off2, off3,
                                         cur0, cur1, cur2, cur3);
  csr_bucket_kernel<<<(20016 + 255) / 256, 256, 0, stream>>>(
      up0_rows, up1_rows, up2_rows, up3_rows,
      up0_cols, up1_cols, up2_cols, up3_cols,
      up0_vals, up1_vals, up2_vals, up3_vals,
      cur0, cur1, cur2, cur3, pk0, pk1, pk2, pk3);

  // ---- weights -> bf16 ----
  cvt_all_kernel<<<(281088 + 255) / 256, 256, 0, stream>>>(W1, W2, W3, W4, Wf, wbuf);

  // ---- dense: latent -> [20][64][128] bf16 (vt-major) ----
  linear0_kernel<<<(64 * 2560 + 255) / 256, 256, 0, stream>>>(latent, W0, b0, convout);

  // ---- level 3: pool 20->79 (C=128), conv 128->128 ----
  pool_csr_kernel<128, 16><<<(N3 * 4 * 128 + 255) / 256, 256, 0, stream>>>(
      convout, off3, pk3, poolbuf, N3);
  conv_mfma_kernel<128, 128, 1, 1><<<dim3(N3, 4), 64, 0, stream>>>(
      poolbuf, spiral3, W1b, b1, convout);

  // ---- level 2: pool 79->314 (C=128), conv 128->64 ----
  pool_csr_kernel<128, 16><<<(N2 * 4 * 128 + 255) / 256, 256, 0, stream>>>(
      convout, off2, pk2, poolbuf, N2);
  conv_mfma_kernel<128, 64, 1, 1><<<dim3(N2, 4), 64, 0, stream>>>(
      poolbuf, spiral2, W2b, b2, convout);

  // ---- level 1: pool 314->1256 (C=64), conv 64->64 (WV=2,MT=2: R7 best) ----
  pool_csr_kernel<64, 16><<<(N1 * 4 * 64 + 255) / 256, 256, 0, stream>>>(
      convout, off1, pk1, poolbuf, N1);
  conv_mfma_kernel<64, 64, 2, 2><<<dim3(N1, 1), 128, 0, stream>>>(
      poolbuf, spiral1, W3b, b3, convout);

  // ---- level 0: pool 1256->5023 (C=64), conv 64->32 (WV=2,MT=2) ----
  pool_csr_kernel<64, 16><<<(N0 * 4 * 64 + 255) / 256, 256, 0, stream>>>(
      convout, off0, pk0, poolbuf, N0);
  conv_mfma_kernel<64, 32, 2, 2><<<dim3(N0, 1), 128, 0, stream>>>(
      poolbuf, spiral0, W4b, b4, convout);

  // ---- final conv 32->3: dense Z transform, then once-each gather-sum ----
  final_dense_kernel<<<N0, 256, 0, stream>>>(convout, Wfp, Zbuf);
  final_gather_kernel<<<(N0 * T_FRAMES + 255) / 256, 256, 0, stream>>>(
      Zbuf, spiral0, bf3, actor, out);
}